// Round 5
// baseline (326.338 us; speedup 1.0000x reference)
//
#include <hip/hip_runtime.h>

// ---------------------------------------------------------------------------
// B=8, N=128, XD=256, ED=128, H=8, DF=32, FFX=1024, FFE=512. All I/O fp32.
// softmax over axis=1 + (attn*V).sum(1) collapses to V => newX = (x@wv+bv)@wxo+bxo.
// bf16 MFMA 16x16x32, fp32 accumulate. Verified layouts:
//   A-frag: lane holds A[m=lane&15][k=(lane>>4)*8 + j], j=0..7
//   B-frag: lane holds B[k=(lane>>4)*8+j][n=lane&15]  (pre-packed contiguous)
//   C/D   : col=lane&15, row=(lane>>4)*4 + reg
// History: R7 reg-blocking 245->167us. R8 (256,4) VGPR-clamp spills FAILED.
// R9 (256,3)+34KB LDS: occupancy +, dur flat -> occupancy not the limiter.
// R10 64-row/512-thr blocks: weight traffic & phases halved, dur 165->156 only
// -> traffic/phase-count not the limiter either.
// R11: latency pipeline. Weight loads have NO LDS dependency but sat after
// each __syncthreads (compiler can't hoist across fence). Hoist Stage B+C
// weights + q/biases to kernel top (land under e-load); double-buffer FF
// weights one quarter ahead with static register names. Stage B loop
// inverted (mt outer) so A-frags load once per mt (halves B ds_reads,
// undoes R10 bank-conflict 3x). VGPR target <=170 per (512,3); spill
// diagnostic = WRITE_SIZE (must stay 66.5MB).
// ---------------------------------------------------------------------------

#define RSQRT_DF 0.17677669529663687f  // 1/sqrt(32)

typedef __attribute__((ext_vector_type(8))) short short8;
typedef __attribute__((ext_vector_type(4))) short short4v;
typedef __attribute__((ext_vector_type(4))) float f32x4;

__device__ __forceinline__ short f2bs(float f) {  // fp32->bf16 bits, RNE
    unsigned u = __float_as_uint(f);
    unsigned r = u + 0x7FFFu + ((u >> 16) & 1u);
    return (short)(r >> 16);
}
__device__ __forceinline__ float bs2f(short s) {  // bf16 bits->fp32
    return __uint_as_float(((unsigned)(unsigned short)s) << 16);
}

// ---------------- single-launch weight pack (all 11 weights) ----------------
struct PackArgs {
    const float* W[11];
    short* Wp[11];
    int kdiv[11];   // K/32
    int N[11];
    int start[12];  // prefix sums of per-weight group counts; start[11]=total
};

__global__ __launch_bounds__(256) void pack_all(PackArgs pa) {
    int g = blockIdx.x * 256 + threadIdx.x;
    if (g >= pa.start[11]) return;
    int i = 0;
    while (g >= pa.start[i + 1]) ++i;
    int local = g - pa.start[i];
    int kdiv = pa.kdiv[i], N = pa.N[i];
    int lane = local & 63, rest = local >> 6;
    int kb = rest % kdiv, nt = rest / kdiv;
    int n = nt * 16 + (lane & 15);
    int k0 = kb * 32 + ((lane >> 4) << 3);
    const float* W = pa.W[i];
    short8 v;
#pragma unroll
    for (int j = 0; j < 8; ++j) v[j] = f2bs(W[(size_t)(k0 + j) * N + n]);
    *(short8*)(pa.Wp[i] + (size_t)local * 8) = v;
}

// ---------------- Q/K GEMM (feeds e-path) ----------------------------------
__global__ __launch_bounds__(256) void qk_gemm(
    const float* __restrict__ x,
    const short* __restrict__ wqP, const short* __restrict__ wkP,
    const float* __restrict__ bq, const float* __restrict__ bk,
    float* __restrict__ Qb, float* __restrict__ Kb) {
    __shared__ short sXb[16 * 264];
    const int t = threadIdx.x, wave = t >> 6, lane = t & 63;
    const int quad = lane >> 4, l15 = lane & 15;
    const int m0 = (blockIdx.x & 63) * 16;
    const int isK = blockIdx.x >> 6;
    const short* wP = isK ? wkP : wqP;
    const float* bp = isK ? bk : bq;
    float* outp = isK ? Kb : Qb;

    const float4* x4 = (const float4*)(x + (size_t)m0 * 256);
    for (int g = t; g < 1024; g += 256) {
        float4 v = x4[g];
        int row = g >> 6, col4 = (g & 63) * 4;
        short4v sv = {f2bs(v.x), f2bs(v.y), f2bs(v.z), f2bs(v.w)};
        *(short4v*)(sXb + row * 264 + col4) = sv;
    }
    __syncthreads();

#pragma unroll 2
    for (int p = 0; p < 4; ++p) {
        int nt = wave * 4 + p;
        f32x4 acc = (f32x4){0.f, 0.f, 0.f, 0.f};
        const short* aB = sXb + l15 * 264 + quad * 8;
        const short* bB = wP + ((size_t)(nt * 8) * 64 + lane) * 8;
#pragma unroll
        for (int kb = 0; kb < 8; ++kb) {
            short8 a = *(const short8*)(aB + kb * 32);
            short8 w = *(const short8*)(bB + (size_t)kb * 512);
            acc = __builtin_amdgcn_mfma_f32_16x16x32_bf16(a, w, acc, 0, 0, 0);
        }
        int col = nt * 16 + l15;
        float bvv = bp[col];
#pragma unroll
        for (int r = 0; r < 4; ++r)
            outp[(size_t)(m0 + quad * 4 + r) * 256 + col] = acc[r] + bvv;
    }
}

// ---------------- fused main: 32 x-blocks + 2048 e-blocks, 512 thr --------
// LDS 68608 B -> 2 blocks/CU. e-path (64 rows):
//   sEb@0 [64][136] 17408 | R_Y@17408 33792: sYb[64][264] -> sTb[64][136]
//   -> sH2 f32 [64][132] | R_R@51200 17408: sR[64][136] bf16 -> sH1[64][136]
// x-path (32 rows): sXb@0 16896 | sVb@16896 | sTbx@33792 |
//   R@50688 16896: sRx bf16 -> sH1x quarter -> sH2x bf16
__global__ __launch_bounds__(512, 3) void fused_main(
    const float* __restrict__ x, const float* __restrict__ e,
    const float* __restrict__ Qb, const float* __restrict__ Kb,
    const short* __restrict__ wvP, const short* __restrict__ wxoP,
    const short* __restrict__ wx1P, const short* __restrict__ wx2P,
    const short* __restrict__ wemP, const short* __restrict__ weaP,
    const short* __restrict__ weoP, const short* __restrict__ we1P,
    const short* __restrict__ we2P,
    const float* __restrict__ bv, const float* __restrict__ bxo,
    const float* __restrict__ bx1, const float* __restrict__ bx2,
    const float* __restrict__ bem, const float* __restrict__ bea,
    const float* __restrict__ beo, const float* __restrict__ be1,
    const float* __restrict__ be2,
    const float* __restrict__ gnx, const float* __restrict__ bnx,
    const float* __restrict__ gne, const float* __restrict__ bne,
    float* __restrict__ xout, float* __restrict__ eout) {
    __shared__ __align__(16) char ldsbuf[68608];
    const int t = threadIdx.x, wave = t >> 6, lane = t & 63;
    const int quad = lane >> 4, l15 = lane & 15;

    if (blockIdx.x < 32) {
        // ================= x-path (32 rows per block, 8 waves) ==============
        short* sXb  = (short*)ldsbuf;              // [32][264] bf16 x
        short* sVb  = (short*)(ldsbuf + 16896);    // [32][264] V bf16
        short* sTbx = (short*)(ldsbuf + 33792);    // [32][264] LN1 out
        short* sRx  = (short*)(ldsbuf + 50688);    // [32][264] newX bf16
        short* sH1x = (short*)(ldsbuf + 50688);    // alias: FF1 quarter
        short* sH2x = (short*)(ldsbuf + 50688);    // alias: FF2 out bf16
        const int m0 = blockIdx.x * 32;

        const float4* x4 = (const float4*)(x + (size_t)m0 * 256);
        for (int g = t; g < 2048; g += 512) {
            float4 v = x4[g];
            int row = g >> 6, col4 = (g & 63) * 4;
            short4v sv = {f2bs(v.x), f2bs(v.y), f2bs(v.z), f2bs(v.w)};
            *(short4v*)(sXb + row * 264 + col4) = sv;
        }
        __syncthreads();

        // V = x @ wv + bv -> sVb bf16
#pragma unroll
        for (int ntl = 0; ntl < 2; ++ntl) {
            const int nt = wave * 2 + ntl;
            const short* bB = wvP + ((size_t)(nt * 8) * 64 + lane) * 8;
            short8 w[8];
#pragma unroll
            for (int kb = 0; kb < 8; ++kb) w[kb] = *(const short8*)(bB + (size_t)kb * 512);
            const int col = nt * 16 + l15;
            const float bvv = bv[col];
#pragma unroll
            for (int mt = 0; mt < 2; ++mt) {
                f32x4 acc = (f32x4){0.f, 0.f, 0.f, 0.f};
#pragma unroll
                for (int kb = 0; kb < 8; ++kb) {
                    short8 a = *(const short8*)(sXb + (mt * 16 + l15) * 264 + quad * 8 + kb * 32);
                    acc = __builtin_amdgcn_mfma_f32_16x16x32_bf16(a, w[kb], acc, 0, 0, 0);
                }
#pragma unroll
                for (int r = 0; r < 4; ++r)
                    sVb[(mt * 16 + quad * 4 + r) * 264 + col] = f2bs(acc[r] + bvv);
            }
        }
        __syncthreads();

        // newX = V @ wxo + bxo -> sRx bf16
#pragma unroll
        for (int ntl = 0; ntl < 2; ++ntl) {
            const int nt = wave * 2 + ntl;
            const short* bB = wxoP + ((size_t)(nt * 8) * 64 + lane) * 8;
            short8 w[8];
#pragma unroll
            for (int kb = 0; kb < 8; ++kb) w[kb] = *(const short8*)(bB + (size_t)kb * 512);
            const int col = nt * 16 + l15;
            const float bvv = bxo[col];
#pragma unroll
            for (int mt = 0; mt < 2; ++mt) {
                f32x4 acc = (f32x4){0.f, 0.f, 0.f, 0.f};
#pragma unroll
                for (int kb = 0; kb < 8; ++kb) {
                    short8 a = *(const short8*)(sVb + (mt * 16 + l15) * 264 + quad * 8 + kb * 32);
                    acc = __builtin_amdgcn_mfma_f32_16x16x32_bf16(a, w[kb], acc, 0, 0, 0);
                }
#pragma unroll
                for (int r = 0; r < 4; ++r)
                    sRx[(mt * 16 + quad * 4 + r) * 264 + col] = f2bs(acc[r] + bvv);
            }
        }
        __syncthreads();

        // LN1 -> sTbx bf16 (4 rows per wave)
        for (int rr = 0; rr < 4; ++rr) {
            int row = wave * 4 + rr;
            float v[4];
            float s1 = 0.f, s2 = 0.f;
#pragma unroll
            for (int k = 0; k < 4; ++k) {
                v[k] = bs2f(sXb[row * 264 + lane + 64 * k]) + bs2f(sRx[row * 264 + lane + 64 * k]);
                s1 += v[k]; s2 += v[k] * v[k];
            }
            for (int off = 32; off; off >>= 1) {
                s1 += __shfl_down(s1, off);
                s2 += __shfl_down(s2, off);
            }
            s1 = __shfl(s1, 0); s2 = __shfl(s2, 0);
            float mean = s1 * (1.f / 256.f);
            float var = s2 * (1.f / 256.f) - mean * mean;
            float rstd = rsqrtf(var + 1e-5f);
#pragma unroll
            for (int k = 0; k < 4; ++k)
                sTbx[row * 264 + lane + 64 * k] =
                    f2bs((v[k] - mean) * rstd * gnx[lane + 64 * k] + bnx[lane + 64 * k]);
        }
        __syncthreads();

        // FF in 4 quarters of 256 cols; H2 accumulated in registers.
        f32x4 accEx[2][2];
#pragma unroll
        for (int i = 0; i < 2; ++i)
#pragma unroll
            for (int j = 0; j < 2; ++j) accEx[i][j] = (f32x4){0.f, 0.f, 0.f, 0.f};

        for (int q = 0; q < 4; ++q) {
            // H1q = relu(T @ wx1[:, q*256:+256] + bx1)
#pragma unroll
            for (int ntl = 0; ntl < 2; ++ntl) {
                const int ntg = q * 16 + wave * 2 + ntl;
                const short* bB = wx1P + ((size_t)(ntg * 8) * 64 + lane) * 8;
                short8 w[8];
#pragma unroll
                for (int kb = 0; kb < 8; ++kb) w[kb] = *(const short8*)(bB + (size_t)kb * 512);
                const int coll = (wave * 2 + ntl) * 16 + l15;
                const float bvv = bx1[ntg * 16 + l15];
#pragma unroll
                for (int mt = 0; mt < 2; ++mt) {
                    f32x4 acc = (f32x4){0.f, 0.f, 0.f, 0.f};
#pragma unroll
                    for (int kb = 0; kb < 8; ++kb) {
                        short8 a = *(const short8*)(sTbx + (mt * 16 + l15) * 264 + quad * 8 + kb * 32);
                        acc = __builtin_amdgcn_mfma_f32_16x16x32_bf16(a, w[kb], acc, 0, 0, 0);
                    }
#pragma unroll
                    for (int r = 0; r < 4; ++r)
                        sH1x[(mt * 16 + quad * 4 + r) * 264 + coll] = f2bs(fmaxf(acc[r] + bvv, 0.f));
                }
            }
            __syncthreads();
            // H2 += H1q @ wx2[q*256:+256, :]
#pragma unroll
            for (int ntl = 0; ntl < 2; ++ntl) {
                const int nt = wave * 2 + ntl;
                const short* bB = wx2P + ((size_t)(nt * 32 + q * 8) * 64 + lane) * 8;
                short8 w[8];
#pragma unroll
                for (int kb = 0; kb < 8; ++kb) w[kb] = *(const short8*)(bB + (size_t)kb * 512);
#pragma unroll
                for (int mt = 0; mt < 2; ++mt) {
#pragma unroll
                    for (int kb = 0; kb < 8; ++kb) {
                        short8 a = *(const short8*)(sH1x + (mt * 16 + l15) * 264 + quad * 8 + kb * 32);
                        accEx[ntl][mt] = __builtin_amdgcn_mfma_f32_16x16x32_bf16(a, w[kb], accEx[ntl][mt], 0, 0, 0);
                    }
                }
            }
            __syncthreads();
        }
        // H2 epilogue -> sH2x bf16
#pragma unroll
        for (int ntl = 0; ntl < 2; ++ntl)
#pragma unroll
            for (int mt = 0; mt < 2; ++mt) {
                const int col = (wave * 2 + ntl) * 16 + l15;
                const float bvv = bx2[col];
#pragma unroll
                for (int r = 0; r < 4; ++r)
                    sH2x[(mt * 16 + quad * 4 + r) * 264 + col] = f2bs(accEx[ntl][mt][r] + bvv);
            }
        __syncthreads();

        // LN2 -> xout
        for (int rr = 0; rr < 4; ++rr) {
            int row = wave * 4 + rr;
            float v[4];
            float s1 = 0.f, s2 = 0.f;
#pragma unroll
            for (int k = 0; k < 4; ++k) {
                v[k] = bs2f(sXb[row * 264 + lane + 64 * k]) + bs2f(sH2x[row * 264 + lane + 64 * k]);
                s1 += v[k]; s2 += v[k] * v[k];
            }
            for (int off = 32; off; off >>= 1) {
                s1 += __shfl_down(s1, off);
                s2 += __shfl_down(s2, off);
            }
            s1 = __shfl(s1, 0); s2 = __shfl(s2, 0);
            float mean = s1 * (1.f / 256.f);
            float var = s2 * (1.f / 256.f) - mean * mean;
            float rstd = rsqrtf(var + 1e-5f);
#pragma unroll
            for (int k = 0; k < 4; ++k)
                xout[(size_t)(m0 + row) * 256 + lane + 64 * k] =
                    (v[k] - mean) * rstd * gnx[lane + 64 * k] + bnx[lane + 64 * k];
        }
        return;
    }

    // ==================== e-path (64 rows per block, 8 waves) ===============
    short* sEb = (short*)ldsbuf;               // [64][136] bf16 e
    short* sYb = (short*)(ldsbuf + 17408);     // [64][264] Y bf16
    short* sTb = (short*)(ldsbuf + 17408);     // alias: [64][136] LN1 out
    float* sH2 = (float*)(ldsbuf + 17408);     // alias: [64][132] FF2 out f32
    short* sR  = (short*)(ldsbuf + 51200);     // [64][136] newE bf16
    short* sH1 = (short*)(ldsbuf + 51200);     // alias: [64][136] H1 quarter

    const int r0 = (blockIdx.x - 32) * 64;
    const int b = r0 >> 14;
    const int j0 = r0 & 127;  // 0 or 64: same (b,i) for the whole block

    // ======== hoisted prefetch: everything with no LDS dependency ==========
    const int ntA = wave * 2, ntB = wave * 2 + 1;
    const int colA = ntA * 16 + l15, colB = ntB * 16 + l15;
    // Stage B weights (wem/wea for both nt)
    short8 w1A[4], w2A[4], w1B[4], w2B[4];
    {
        const short* p1A = wemP + ((size_t)(ntA * 4) * 64 + lane) * 8;
        const short* p2A = weaP + ((size_t)(ntA * 4) * 64 + lane) * 8;
        const short* p1B = wemP + ((size_t)(ntB * 4) * 64 + lane) * 8;
        const short* p2B = weaP + ((size_t)(ntB * 4) * 64 + lane) * 8;
#pragma unroll
        for (int kb = 0; kb < 4; ++kb) {
            w1A[kb] = *(const short8*)(p1A + (size_t)kb * 512);
            w2A[kb] = *(const short8*)(p2A + (size_t)kb * 512);
            w1B[kb] = *(const short8*)(p1B + (size_t)kb * 512);
            w2B[kb] = *(const short8*)(p2B + (size_t)kb * 512);
        }
    }
    // Stage C weights (weo, 1 nt = wave)
    short8 wC[8];
    {
        const short* pC = weoP + ((size_t)(wave * 8) * 64 + lane) * 8;
#pragma unroll
        for (int kb = 0; kb < 8; ++kb) wC[kb] = *(const short8*)(pC + (size_t)kb * 512);
    }
    // scalars: q, biases, LN params
    const float qA = Qb[(size_t)(r0 >> 7) * 256 + colA] * RSQRT_DF;
    const float qB = Qb[(size_t)(r0 >> 7) * 256 + colB] * RSQRT_DF;
    const float bmA = bem[colA], baA = bea[colA];
    const float bmB = bem[colB], baB = bea[colB];
    const float boC = beo[wave * 16 + l15];
    const float g0 = gne[lane], g1 = gne[lane + 64];
    const float bn0 = bne[lane], bn1 = bne[lane + 64];

    // ---- load e tile (bf16): 64 rows x 128 cols ----
    {
        const float4* e4 = (const float4*)(e + (size_t)r0 * 128);
        for (int g = t; g < 2048; g += 512) {
            float4 v = e4[g];
            int row = g >> 5, col4 = (g & 31) * 4;
            short4v sv = {f2bs(v.x), f2bs(v.y), f2bs(v.z), f2bs(v.w)};
            *(short4v*)(sEb + row * 136 + col4) = sv;
        }
    }
    __syncthreads();

    // ---- Stage B: mt outer (A-frags once per mt feed both nt's MFMAs) ----
#pragma unroll
    for (int mt = 0; mt < 4; ++mt) {
        const float* kpA = Kb + (size_t)((b << 7) + j0 + mt * 16 + quad * 4) * 256 + colA;
        const float* kpB = Kb + (size_t)((b << 7) + j0 + mt * 16 + quad * 4) * 256 + colB;
        float kvA[4], kvB[4];
#pragma unroll
        for (int r = 0; r < 4; ++r) {
            kvA[r] = kpA[(size_t)r * 256];
            kvB[r] = kpB[(size_t)r * 256];
        }
        short8 aE[4];
#pragma unroll
        for (int kb = 0; kb < 4; ++kb)
            aE[kb] = *(const short8*)(sEb + (mt * 16 + l15) * 136 + quad * 8 + kb * 32);
        f32x4 a1A = (f32x4){0.f, 0.f, 0.f, 0.f}, a2A = (f32x4){0.f, 0.f, 0.f, 0.f};
        f32x4 a1B = (f32x4){0.f, 0.f, 0.f, 0.f}, a2B = (f32x4){0.f, 0.f, 0.f, 0.f};
#pragma unroll
        for (int kb = 0; kb < 4; ++kb) {
            a1A = __builtin_amdgcn_mfma_f32_16x16x32_bf16(aE[kb], w1A[kb], a1A, 0, 0, 0);
            a2A = __builtin_amdgcn_mfma_f32_16x16x32_bf16(aE[kb], w2A[kb], a2A, 0, 0, 0);
            a1B = __builtin_amdgcn_mfma_f32_16x16x32_bf16(aE[kb], w1B[kb], a1B, 0, 0, 0);
            a2B = __builtin_amdgcn_mfma_f32_16x16x32_bf16(aE[kb], w2B[kb], a2B, 0, 0, 0);
        }
#pragma unroll
        for (int r = 0; r < 4; ++r) {
            int row = mt * 16 + quad * 4 + r;
            sYb[row * 264 + colA] = f2bs(qA * kvA[r] * (a1A[r] + bmA + 1.0f) + (a2A[r] + baA));
            sYb[row * 264 + colB] = f2bs(qB * kvB[r] * (a1B[r] + bmB + 1.0f) + (a2B[r] + baB));
        }
    }
    __syncthreads();

    // ---- Stage C: newE = Y @ weo + beo -> sR bf16 (wC already resident) ----
#pragma unroll
    for (int mt = 0; mt < 4; ++mt) {
        f32x4 acc = (f32x4){0.f, 0.f, 0.f, 0.f};
#pragma unroll
        for (int kb = 0; kb < 8; ++kb) {
            short8 a = *(const short8*)(sYb + (mt * 16 + l15) * 264 + quad * 8 + kb * 32);
            acc = __builtin_amdgcn_mfma_f32_16x16x32_bf16(a, wC[kb], acc, 0, 0, 0);
        }
        const int col = wave * 16 + l15;
#pragma unroll
        for (int r = 0; r < 4; ++r)
            sR[(mt * 16 + quad * 4 + r) * 136 + col] = f2bs(acc[r] + boC);
    }
    // prefetch FF quarter 0 weights (consumed after next-next barrier)
    short8 f1w[4], f2w[4];
    {
        const short* p1 = we1P + ((size_t)((0 * 8 + wave) * 4) * 64 + lane) * 8;
        const short* p2 = we2P + ((size_t)(wave * 16 + 0 * 4) * 64 + lane) * 8;
#pragma unroll
        for (int kb = 0; kb < 4; ++kb) {
            f1w[kb] = *(const short8*)(p1 + (size_t)kb * 512);
            f2w[kb] = *(const short8*)(p2 + (size_t)kb * 512);
        }
    }
    __syncthreads();

    // ---- LN1: sTb = bf16(LN(e + newE)*gne + bne) ----
    for (int rr = 0; rr < 8; ++rr) {
        int row = wave * 8 + rr;
        float v0 = bs2f(sEb[row * 136 + lane]) + bs2f(sR[row * 136 + lane]);
        float v1 = bs2f(sEb[row * 136 + lane + 64]) + bs2f(sR[row * 136 + lane + 64]);
        float s1 = v0 + v1, s2 = v0 * v0 + v1 * v1;
        for (int off = 32; off; off >>= 1) {
            s1 += __shfl_down(s1, off);
            s2 += __shfl_down(s2, off);
        }
        s1 = __shfl(s1, 0); s2 = __shfl(s2, 0);
        float mean = s1 * 0.0078125f;
        float var = s2 * 0.0078125f - mean * mean;
        float rstd = rsqrtf(var + 1e-5f);
        sTb[row * 136 + lane]      = f2bs((v0 - mean) * rstd * g0 + bn0);
        sTb[row * 136 + lane + 64] = f2bs((v1 - mean) * rstd * g1 + bn1);
    }
    __syncthreads();

    // ---- FF in 4 quarters; weights double-buffered one quarter ahead ----
    f32x4 accE[4];
#pragma unroll
    for (int p = 0; p < 4; ++p) accE[p] = (f32x4){0.f, 0.f, 0.f, 0.f};

#pragma unroll
    for (int q = 0; q < 4; ++q) {
        // issue next quarter's FF1 weights (consumed after 2 barriers)
        short8 f1n[4];
        if (q < 3) {
            const short* p1 = we1P + ((size_t)(((q + 1) * 8 + wave) * 4) * 64 + lane) * 8;
#pragma unroll
            for (int kb = 0; kb < 4; ++kb) f1n[kb] = *(const short8*)(p1 + (size_t)kb * 512);
        }
        // H1q = relu(T @ we1[:, q*128:+128] + be1)  (uses resident f1w)
        {
            const int coll = wave * 16 + l15;
            const float bvv = be1[(q * 8 + wave) * 16 + l15];
#pragma unroll
            for (int mt = 0; mt < 4; ++mt) {
                f32x4 acc = (f32x4){0.f, 0.f, 0.f, 0.f};
#pragma unroll
                for (int kb = 0; kb < 4; ++kb) {
                    short8 a = *(const short8*)(sTb + (mt * 16 + l15) * 136 + quad * 8 + kb * 32);
                    acc = __builtin_amdgcn_mfma_f32_16x16x32_bf16(a, f1w[kb], acc, 0, 0, 0);
                }
#pragma unroll
                for (int r = 0; r < 4; ++r)
                    sH1[(mt * 16 + quad * 4 + r) * 136 + coll] = f2bs(fmaxf(acc[r] + bvv, 0.f));
            }
        }
        __syncthreads();
        // issue next quarter's FF2 weights (consumed after 2 barriers)
        short8 f2n[4];
        if (q < 3) {
            const short* p2 = we2P + ((size_t)(wave * 16 + (q + 1) * 4) * 64 + lane) * 8;
#pragma unroll
            for (int kb = 0; kb < 4; ++kb) f2n[kb] = *(const short8*)(p2 + (size_t)kb * 512);
        }
        // H2 += H1q @ we2[q*128:+128, :]  (uses resident f2w)
#pragma unroll
        for (int mt = 0; mt < 4; ++mt) {
#pragma unroll
            for (int kb = 0; kb < 4; ++kb) {
                short8 a = *(const short8*)(sH1 + (mt * 16 + l15) * 136 + quad * 8 + kb * 32);
                accE[mt] = __builtin_amdgcn_mfma_f32_16x16x32_bf16(a, f2w[kb], accE[mt], 0, 0, 0);
            }
        }
        __syncthreads();
        if (q < 3) {
#pragma unroll
            for (int kb = 0; kb < 4; ++kb) { f1w[kb] = f1n[kb]; f2w[kb] = f2n[kb]; }
        }
    }
    // epilogue -> sH2 f32 (over dead sTb/sYb region)
    {
        const int col = wave * 16 + l15;
        const float bvv = be2[col];
#pragma unroll
        for (int mt = 0; mt < 4; ++mt)
#pragma unroll
            for (int r = 0; r < 4; ++r)
                sH2[(mt * 16 + quad * 4 + r) * 132 + col] = accE[mt][r] + bvv;
    }
    __syncthreads();

    // ---- LN2 -> global ----
    for (int rr = 0; rr < 8; ++rr) {
        int row = wave * 8 + rr;
        float v0 = bs2f(sEb[row * 136 + lane]) + sH2[row * 132 + lane];
        float v1 = bs2f(sEb[row * 136 + lane + 64]) + sH2[row * 132 + lane + 64];
        float s1 = v0 + v1, s2 = v0 * v0 + v1 * v1;
        for (int off = 32; off; off >>= 1) {
            s1 += __shfl_down(s1, off);
            s2 += __shfl_down(s2, off);
        }
        s1 = __shfl(s1, 0); s2 = __shfl(s2, 0);
        float mean = s1 * 0.0078125f;
        float var = s2 * 0.0078125f - mean * mean;
        float rstd = rsqrtf(var + 1e-5f);
        size_t o = (size_t)(r0 + row) * 128;
        eout[o + lane]      = (v0 - mean) * rstd * g0 + bn0;
        eout[o + lane + 64] = (v1 - mean) * rstd * g1 + bn1;
    }
}

extern "C" void kernel_launch(void* const* d_in, const int* in_sizes, int n_in,
                              void* d_out, int out_size, void* d_ws, size_t ws_size,
                              hipStream_t stream) {
    const float* x   = (const float*)d_in[0];
    const float* e   = (const float*)d_in[1];
    const float* wq  = (const float*)d_in[2];
    const float* wk  = (const float*)d_in[3];
    const float* wv  = (const float*)d_in[4];
    const float* wem = (const float*)d_in[5];
    const float* wea = (const float*)d_in[6];
    const float* wxo = (const float*)d_in[7];
    const float* weo = (const float*)d_in[8];
    const float* wx1 = (const float*)d_in[9];
    const float* wx2 = (const float*)d_in[10];
    const float* we1 = (const float*)d_in[11];
    const float* we2 = (const float*)d_in[12];
    const float* bq  = (const float*)d_in[13];
    const float* bk  = (const float*)d_in[14];
    const float* bv  = (const float*)d_in[15];
    const float* bem = (const float*)d_in[16];
    const float* bea = (const float*)d_in[17];
    const float* bxo = (const float*)d_in[18];
    const float* beo = (const float*)d_in[19];
    const float* bx1 = (const float*)d_in[20];
    const float* bx2 = (const float*)d_in[21];
    const float* be1 = (const float*)d_in[22];
    const float* be2 = (const float*)d_in[23];
    const float* gnx = (const float*)d_in[24];
    const float* bnx = (const float*)d_in[25];
    const float* gne = (const float*)d_in[26];
    const float* bne = (const float*)d_in[27];

    float* out = (float*)d_out;  // x_out (262144) then e_out (16777216)

    float* ws = (float*)d_ws;
    float* Qb = ws;               // 262144 f32
    float* Kb = Qb + 262144;      // 262144 f32
    short* base = (short*)(Kb + 262144);
    short* wqP  = base;           // 65536
    short* wkP  = wqP + 65536;
    short* wvP  = wkP + 65536;
    short* wxoP = wvP + 65536;
    short* wx1P = wxoP + 65536;   // 262144
    short* wx2P = wx1P + 262144;  // 262144
    short* wemP = wx2P + 262144;  // 32768
    short* weaP = wemP + 32768;
    short* weoP = weaP + 32768;
    short* we1P = weoP + 32768;   // 65536
    short* we2P = we1P + 65536;   // 65536

    // ---- one pack launch for all 11 weights ----
    PackArgs pa;
    const float* Ws[11] = {wq, wk, wv, wxo, wx1, wx2, wem, wea, weo, we1, we2};
    short* Wps[11] = {wqP, wkP, wvP, wxoP, wx1P, wx2P, wemP, weaP, weoP, we1P, we2P};
    int Ks[11] = {256, 256, 256, 256, 256, 1024, 128, 128, 256, 128, 512};
    int Ns[11] = {256, 256, 256, 256, 1024, 256, 256, 256, 128, 512, 128};
    int acc = 0;
    for (int i = 0; i < 11; ++i) {
        pa.W[i] = Ws[i];
        pa.Wp[i] = Wps[i];
        pa.kdiv[i] = Ks[i] >> 5;
        pa.N[i] = Ns[i];
        pa.start[i] = acc;
        acc += (Ns[i] >> 4) * (Ks[i] >> 5) * 64;
    }
    pa.start[11] = acc;
    pack_all<<<(acc + 255) / 256, 256, 0, stream>>>(pa);

    // ---- Q/K GEMM (only cross-path dependency) ----
    qk_gemm<<<128, 256, 0, stream>>>(x, wqP, wkP, bq, bk, Qb, Kb);

    // ---- fused main: 32 x-blocks (first, overlap) + 2048 e-path ----
    fused_main<<<2080, 512, 0, stream>>>(
        x, e, Qb, Kb, wvP, wxoP, wx1P, wx2P, wemP, weaP, weoP, we1P, we2P,
        bv, bxo, bx1, bx2, bem, bea, beo, be1, be2,
        gnx, bnx, gne, bne, out, out + 262144);
}

// Round 6
// 290.846 us; speedup vs baseline: 1.1220x; 1.1220x over previous
//
#include <hip/hip_runtime.h>

// ---------------------------------------------------------------------------
// B=8, N=128, XD=256, ED=128, H=8, DF=32, FFX=1024, FFE=512. All I/O fp32.
// softmax over axis=1 + (attn*V).sum(1) collapses to V => newX = (x@wv+bv)@wxo+bxo.
// bf16 MFMA 16x16x32, fp32 accumulate. Verified layouts:
//   A-frag: lane holds A[m=lane&15][k=(lane>>4)*8 + j], j=0..7
//   B-frag: lane holds B[k=(lane>>4)*8+j][n=lane&15]  (pre-packed contiguous)
//   C/D   : col=lane&15, row=(lane>>4)*4 + reg
// KEY SYMMETRY: A-frag and B-frag have the same lane mapping, so the packed
// weights W[k][n] serve unchanged as A = W^T, and a row-fragment serves as B.
// mfma(Wfrag, rowfrag, acc) yields D^T: lane holds out[row=l15][4 consecutive
// cols = 16*ct + quad*4 + r] -> vectorized epilogues.
// History: R7 reg-block 245->167. R8 (256,4) clamp+spill FAIL. R9 occupancy
// neutral. R10 64-row/512thr 165->156. R11 cross-barrier hoist FAIL (VGPR
// 84 + occupancy 38->21, dur 198) — long-lived prefetch regs kill residency.
// R12: revert to R10 base + transposed-output epilogues everywhere in e-path:
// Y/sR/sH1 writes b16 scalar x4 -> short4v x1; Stage B K-loads strided
// scalar x4 -> float4; q/bias float4 per col-tile. Same MFMA count/order,
// same buffer contents. Targets SQ_LDS_BANK_CONFLICT 12.85M.
// block=512: __launch_bounds__(512,3); keep live regs short-lived (R11).
// ---------------------------------------------------------------------------

#define RSQRT_DF 0.17677669529663687f  // 1/sqrt(32)

typedef __attribute__((ext_vector_type(8))) short short8;
typedef __attribute__((ext_vector_type(4))) short short4v;
typedef __attribute__((ext_vector_type(4))) float f32x4;

__device__ __forceinline__ short f2bs(float f) {  // fp32->bf16 bits, RNE
    unsigned u = __float_as_uint(f);
    unsigned r = u + 0x7FFFu + ((u >> 16) & 1u);
    return (short)(r >> 16);
}
__device__ __forceinline__ float bs2f(short s) {  // bf16 bits->fp32
    return __uint_as_float(((unsigned)(unsigned short)s) << 16);
}

// ---------------- single-launch weight pack (all 11 weights) ----------------
struct PackArgs {
    const float* W[11];
    short* Wp[11];
    int kdiv[11];   // K/32
    int N[11];
    int start[12];  // prefix sums of per-weight group counts; start[11]=total
};

__global__ __launch_bounds__(256) void pack_all(PackArgs pa) {
    int g = blockIdx.x * 256 + threadIdx.x;
    if (g >= pa.start[11]) return;
    int i = 0;
    while (g >= pa.start[i + 1]) ++i;
    int local = g - pa.start[i];
    int kdiv = pa.kdiv[i], N = pa.N[i];
    int lane = local & 63, rest = local >> 6;
    int kb = rest % kdiv, nt = rest / kdiv;
    int n = nt * 16 + (lane & 15);
    int k0 = kb * 32 + ((lane >> 4) << 3);
    const float* W = pa.W[i];
    short8 v;
#pragma unroll
    for (int j = 0; j < 8; ++j) v[j] = f2bs(W[(size_t)(k0 + j) * N + n]);
    *(short8*)(pa.Wp[i] + (size_t)local * 8) = v;
}

// ---------------- Q/K GEMM (feeds e-path) ----------------------------------
__global__ __launch_bounds__(256) void qk_gemm(
    const float* __restrict__ x,
    const short* __restrict__ wqP, const short* __restrict__ wkP,
    const float* __restrict__ bq, const float* __restrict__ bk,
    float* __restrict__ Qb, float* __restrict__ Kb) {
    __shared__ short sXb[16 * 264];
    const int t = threadIdx.x, wave = t >> 6, lane = t & 63;
    const int quad = lane >> 4, l15 = lane & 15;
    const int m0 = (blockIdx.x & 63) * 16;
    const int isK = blockIdx.x >> 6;
    const short* wP = isK ? wkP : wqP;
    const float* bp = isK ? bk : bq;
    float* outp = isK ? Kb : Qb;

    const float4* x4 = (const float4*)(x + (size_t)m0 * 256);
    for (int g = t; g < 1024; g += 256) {
        float4 v = x4[g];
        int row = g >> 6, col4 = (g & 63) * 4;
        short4v sv = {f2bs(v.x), f2bs(v.y), f2bs(v.z), f2bs(v.w)};
        *(short4v*)(sXb + row * 264 + col4) = sv;
    }
    __syncthreads();

#pragma unroll 2
    for (int p = 0; p < 4; ++p) {
        int nt = wave * 4 + p;
        f32x4 acc = (f32x4){0.f, 0.f, 0.f, 0.f};
        const short* aB = sXb + l15 * 264 + quad * 8;
        const short* bB = wP + ((size_t)(nt * 8) * 64 + lane) * 8;
#pragma unroll
        for (int kb = 0; kb < 8; ++kb) {
            short8 a = *(const short8*)(aB + kb * 32);
            short8 w = *(const short8*)(bB + (size_t)kb * 512);
            acc = __builtin_amdgcn_mfma_f32_16x16x32_bf16(a, w, acc, 0, 0, 0);
        }
        int col = nt * 16 + l15;
        float bvv = bp[col];
#pragma unroll
        for (int r = 0; r < 4; ++r)
            outp[(size_t)(m0 + quad * 4 + r) * 256 + col] = acc[r] + bvv;
    }
}

// ---------------- fused main: 32 x-blocks + 2048 e-blocks, 512 thr --------
// LDS 68608 B -> 2 blocks/CU. e-path (64 rows):
//   sEb@0 [64][136] 17408 | R_Y@17408 33792: sYb[64][264] -> sTb[64][136]
//   -> sH2 f32 [64][132] | R_R@51200 17408: sR[64][136] bf16 -> sH1[64][136]
// x-path (32 rows): sXb@0 16896 | sVb@16896 | sTbx@33792 |
//   R@50688 16896: sRx bf16 -> sH1x quarter -> sH2x bf16
__global__ __launch_bounds__(512, 3) void fused_main(
    const float* __restrict__ x, const float* __restrict__ e,
    const float* __restrict__ Qb, const float* __restrict__ Kb,
    const short* __restrict__ wvP, const short* __restrict__ wxoP,
    const short* __restrict__ wx1P, const short* __restrict__ wx2P,
    const short* __restrict__ wemP, const short* __restrict__ weaP,
    const short* __restrict__ weoP, const short* __restrict__ we1P,
    const short* __restrict__ we2P,
    const float* __restrict__ bv, const float* __restrict__ bxo,
    const float* __restrict__ bx1, const float* __restrict__ bx2,
    const float* __restrict__ bem, const float* __restrict__ bea,
    const float* __restrict__ beo, const float* __restrict__ be1,
    const float* __restrict__ be2,
    const float* __restrict__ gnx, const float* __restrict__ bnx,
    const float* __restrict__ gne, const float* __restrict__ bne,
    float* __restrict__ xout, float* __restrict__ eout) {
    __shared__ __align__(16) char ldsbuf[68608];
    const int t = threadIdx.x, wave = t >> 6, lane = t & 63;
    const int quad = lane >> 4, l15 = lane & 15;

    if (blockIdx.x < 32) {
        // ================= x-path (32 rows per block, 8 waves) ==============
        short* sXb  = (short*)ldsbuf;              // [32][264] bf16 x
        short* sVb  = (short*)(ldsbuf + 16896);    // [32][264] V bf16
        short* sTbx = (short*)(ldsbuf + 33792);    // [32][264] LN1 out
        short* sRx  = (short*)(ldsbuf + 50688);    // [32][264] newX bf16
        short* sH1x = (short*)(ldsbuf + 50688);    // alias: FF1 quarter
        short* sH2x = (short*)(ldsbuf + 50688);    // alias: FF2 out bf16
        const int m0 = blockIdx.x * 32;

        const float4* x4 = (const float4*)(x + (size_t)m0 * 256);
        for (int g = t; g < 2048; g += 512) {
            float4 v = x4[g];
            int row = g >> 6, col4 = (g & 63) * 4;
            short4v sv = {f2bs(v.x), f2bs(v.y), f2bs(v.z), f2bs(v.w)};
            *(short4v*)(sXb + row * 264 + col4) = sv;
        }
        __syncthreads();

        // V = x @ wv + bv -> sVb bf16 (transposed-output epilogue)
#pragma unroll
        for (int ctl = 0; ctl < 2; ++ctl) {
            const int ct = wave * 2 + ctl;
            const int c0 = ct * 16 + quad * 4;
            const short* bB = wvP + ((size_t)(ct * 8) * 64 + lane) * 8;
            short8 w[8];
#pragma unroll
            for (int kb = 0; kb < 8; ++kb) w[kb] = *(const short8*)(bB + (size_t)kb * 512);
            const float4 bvv = *(const float4*)(bv + c0);
#pragma unroll
            for (int rt = 0; rt < 2; ++rt) {
                const int row = rt * 16 + l15;
                f32x4 acc = (f32x4){0.f, 0.f, 0.f, 0.f};
#pragma unroll
                for (int kb = 0; kb < 8; ++kb) {
                    short8 bf = *(const short8*)(sXb + row * 264 + quad * 8 + kb * 32);
                    acc = __builtin_amdgcn_mfma_f32_16x16x32_bf16(w[kb], bf, acc, 0, 0, 0);
                }
                short4v vv = {f2bs(acc[0] + bvv.x), f2bs(acc[1] + bvv.y),
                              f2bs(acc[2] + bvv.z), f2bs(acc[3] + bvv.w)};
                *(short4v*)(sVb + row * 264 + c0) = vv;
            }
        }
        __syncthreads();

        // newX = V @ wxo + bxo -> sRx bf16
#pragma unroll
        for (int ctl = 0; ctl < 2; ++ctl) {
            const int ct = wave * 2 + ctl;
            const int c0 = ct * 16 + quad * 4;
            const short* bB = wxoP + ((size_t)(ct * 8) * 64 + lane) * 8;
            short8 w[8];
#pragma unroll
            for (int kb = 0; kb < 8; ++kb) w[kb] = *(const short8*)(bB + (size_t)kb * 512);
            const float4 bvv = *(const float4*)(bxo + c0);
#pragma unroll
            for (int rt = 0; rt < 2; ++rt) {
                const int row = rt * 16 + l15;
                f32x4 acc = (f32x4){0.f, 0.f, 0.f, 0.f};
#pragma unroll
                for (int kb = 0; kb < 8; ++kb) {
                    short8 bf = *(const short8*)(sVb + row * 264 + quad * 8 + kb * 32);
                    acc = __builtin_amdgcn_mfma_f32_16x16x32_bf16(w[kb], bf, acc, 0, 0, 0);
                }
                short4v vv = {f2bs(acc[0] + bvv.x), f2bs(acc[1] + bvv.y),
                              f2bs(acc[2] + bvv.z), f2bs(acc[3] + bvv.w)};
                *(short4v*)(sRx + row * 264 + c0) = vv;
            }
        }
        __syncthreads();

        // LN1 -> sTbx bf16 (4 rows per wave)
        for (int rr = 0; rr < 4; ++rr) {
            int row = wave * 4 + rr;
            float v[4];
            float s1 = 0.f, s2 = 0.f;
#pragma unroll
            for (int k = 0; k < 4; ++k) {
                v[k] = bs2f(sXb[row * 264 + lane + 64 * k]) + bs2f(sRx[row * 264 + lane + 64 * k]);
                s1 += v[k]; s2 += v[k] * v[k];
            }
            for (int off = 32; off; off >>= 1) {
                s1 += __shfl_down(s1, off);
                s2 += __shfl_down(s2, off);
            }
            s1 = __shfl(s1, 0); s2 = __shfl(s2, 0);
            float mean = s1 * (1.f / 256.f);
            float var = s2 * (1.f / 256.f) - mean * mean;
            float rstd = rsqrtf(var + 1e-5f);
#pragma unroll
            for (int k = 0; k < 4; ++k)
                sTbx[row * 264 + lane + 64 * k] =
                    f2bs((v[k] - mean) * rstd * gnx[lane + 64 * k] + bnx[lane + 64 * k]);
        }
        __syncthreads();

        // FF in 4 quarters of 256 cols; H2 accumulated in registers.
        f32x4 accEx[2][2];
#pragma unroll
        for (int i = 0; i < 2; ++i)
#pragma unroll
            for (int j = 0; j < 2; ++j) accEx[i][j] = (f32x4){0.f, 0.f, 0.f, 0.f};

        for (int q = 0; q < 4; ++q) {
            // H1q = relu(T @ wx1[:, q*256:+256] + bx1)
#pragma unroll
            for (int ctl = 0; ctl < 2; ++ctl) {
                const int ctg = q * 16 + wave * 2 + ctl;
                const int c0 = (wave * 2 + ctl) * 16 + quad * 4;
                const short* bB = wx1P + ((size_t)(ctg * 8) * 64 + lane) * 8;
                short8 w[8];
#pragma unroll
                for (int kb = 0; kb < 8; ++kb) w[kb] = *(const short8*)(bB + (size_t)kb * 512);
                const float4 bvv = *(const float4*)(bx1 + ctg * 16 + quad * 4);
#pragma unroll
                for (int rt = 0; rt < 2; ++rt) {
                    const int row = rt * 16 + l15;
                    f32x4 acc = (f32x4){0.f, 0.f, 0.f, 0.f};
#pragma unroll
                    for (int kb = 0; kb < 8; ++kb) {
                        short8 bf = *(const short8*)(sTbx + row * 264 + quad * 8 + kb * 32);
                        acc = __builtin_amdgcn_mfma_f32_16x16x32_bf16(w[kb], bf, acc, 0, 0, 0);
                    }
                    short4v hv = {f2bs(fmaxf(acc[0] + bvv.x, 0.f)), f2bs(fmaxf(acc[1] + bvv.y, 0.f)),
                                  f2bs(fmaxf(acc[2] + bvv.z, 0.f)), f2bs(fmaxf(acc[3] + bvv.w, 0.f))};
                    *(short4v*)(sH1x + row * 264 + c0) = hv;
                }
            }
            __syncthreads();
            // H2 += H1q @ wx2[q*256:+256, :]
#pragma unroll
            for (int ctl = 0; ctl < 2; ++ctl) {
                const int ct = wave * 2 + ctl;
                const short* bB = wx2P + ((size_t)(ct * 32 + q * 8) * 64 + lane) * 8;
                short8 w[8];
#pragma unroll
                for (int kb = 0; kb < 8; ++kb) w[kb] = *(const short8*)(bB + (size_t)kb * 512);
#pragma unroll
                for (int rt = 0; rt < 2; ++rt) {
                    const int row = rt * 16 + l15;
#pragma unroll
                    for (int kb = 0; kb < 8; ++kb) {
                        short8 bf = *(const short8*)(sH1x + row * 264 + quad * 8 + kb * 32);
                        accEx[ctl][rt] = __builtin_amdgcn_mfma_f32_16x16x32_bf16(w[kb], bf, accEx[ctl][rt], 0, 0, 0);
                    }
                }
            }
            __syncthreads();
        }
        // H2 epilogue -> sH2x bf16
#pragma unroll
        for (int ctl = 0; ctl < 2; ++ctl) {
            const int c0 = (wave * 2 + ctl) * 16 + quad * 4;
            const float4 bvv = *(const float4*)(bx2 + c0);
#pragma unroll
            for (int rt = 0; rt < 2; ++rt) {
                const int row = rt * 16 + l15;
                short4v hv = {f2bs(accEx[ctl][rt][0] + bvv.x), f2bs(accEx[ctl][rt][1] + bvv.y),
                              f2bs(accEx[ctl][rt][2] + bvv.z), f2bs(accEx[ctl][rt][3] + bvv.w)};
                *(short4v*)(sH2x + row * 264 + c0) = hv;
            }
        }
        __syncthreads();

        // LN2 -> xout
        for (int rr = 0; rr < 4; ++rr) {
            int row = wave * 4 + rr;
            float v[4];
            float s1 = 0.f, s2 = 0.f;
#pragma unroll
            for (int k = 0; k < 4; ++k) {
                v[k] = bs2f(sXb[row * 264 + lane + 64 * k]) + bs2f(sH2x[row * 264 + lane + 64 * k]);
                s1 += v[k]; s2 += v[k] * v[k];
            }
            for (int off = 32; off; off >>= 1) {
                s1 += __shfl_down(s1, off);
                s2 += __shfl_down(s2, off);
            }
            s1 = __shfl(s1, 0); s2 = __shfl(s2, 0);
            float mean = s1 * (1.f / 256.f);
            float var = s2 * (1.f / 256.f) - mean * mean;
            float rstd = rsqrtf(var + 1e-5f);
#pragma unroll
            for (int k = 0; k < 4; ++k)
                xout[(size_t)(m0 + row) * 256 + lane + 64 * k] =
                    (v[k] - mean) * rstd * gnx[lane + 64 * k] + bnx[lane + 64 * k];
        }
        return;
    }

    // ==================== e-path (64 rows per block, 8 waves) ===============
    short* sEb = (short*)ldsbuf;               // [64][136] bf16 e
    short* sYb = (short*)(ldsbuf + 17408);     // [64][264] Y bf16
    short* sTb = (short*)(ldsbuf + 17408);     // alias: [64][136] LN1 out
    float* sH2 = (float*)(ldsbuf + 17408);     // alias: [64][132] FF2 out f32
    short* sR  = (short*)(ldsbuf + 51200);     // [64][136] newE bf16
    short* sH1 = (short*)(ldsbuf + 51200);     // alias: [64][136] H1 quarter

    const int r0 = (blockIdx.x - 32) * 64;
    const int b = r0 >> 14;
    const int j0 = r0 & 127;  // 0 or 64: same (b,i) for the whole block

    // ---- load e tile (bf16): 64 rows x 128 cols ----
    {
        const float4* e4 = (const float4*)(e + (size_t)r0 * 128);
        for (int g = t; g < 2048; g += 512) {
            float4 v = e4[g];
            int row = g >> 5, col4 = (g & 31) * 4;
            short4v sv = {f2bs(v.x), f2bs(v.y), f2bs(v.z), f2bs(v.w)};
            *(short4v*)(sEb + row * 136 + col4) = sv;
        }
    }
    __syncthreads();

    // ---- Stage B (transposed-output): Y = qk*(E1+1)+E2 -> sYb ----
    // A = wem^T/wea^T (same packed bytes), B = e-rows (same b128 reads).
    // Lane holds Y[row=rt*16+l15][cols c0..c0+3] -> float4 K-load + b64 Y-write.
#pragma unroll
    for (int ctl = 0; ctl < 2; ++ctl) {
        const int ct = wave * 2 + ctl;
        const int c0 = ct * 16 + quad * 4;
        const short* p1 = wemP + ((size_t)(ct * 4) * 64 + lane) * 8;
        const short* p2 = weaP + ((size_t)(ct * 4) * 64 + lane) * 8;
        short8 w1[4], w2[4];
#pragma unroll
        for (int kb = 0; kb < 4; ++kb) {
            w1[kb] = *(const short8*)(p1 + (size_t)kb * 512);
            w2[kb] = *(const short8*)(p2 + (size_t)kb * 512);
        }
        const float4 qv  = *(const float4*)(Qb + (size_t)(r0 >> 7) * 256 + c0);
        const float4 bmv = *(const float4*)(bem + c0);
        const float4 bav = *(const float4*)(bea + c0);
#pragma unroll
        for (int rt = 0; rt < 4; ++rt) {
            const int row = rt * 16 + l15;
            const float4 kv = *(const float4*)(Kb + (size_t)((b << 7) + j0 + row) * 256 + c0);
            f32x4 a1 = (f32x4){0.f, 0.f, 0.f, 0.f};
            f32x4 a2 = (f32x4){0.f, 0.f, 0.f, 0.f};
#pragma unroll
            for (int kb = 0; kb < 4; ++kb) {
                short8 bf = *(const short8*)(sEb + row * 136 + quad * 8 + kb * 32);
                a1 = __builtin_amdgcn_mfma_f32_16x16x32_bf16(w1[kb], bf, a1, 0, 0, 0);
                a2 = __builtin_amdgcn_mfma_f32_16x16x32_bf16(w2[kb], bf, a2, 0, 0, 0);
            }
            short4v yv = {
                f2bs(qv.x * RSQRT_DF * kv.x * (a1[0] + bmv.x + 1.0f) + (a2[0] + bav.x)),
                f2bs(qv.y * RSQRT_DF * kv.y * (a1[1] + bmv.y + 1.0f) + (a2[1] + bav.y)),
                f2bs(qv.z * RSQRT_DF * kv.z * (a1[2] + bmv.z + 1.0f) + (a2[2] + bav.z)),
                f2bs(qv.w * RSQRT_DF * kv.w * (a1[3] + bmv.w + 1.0f) + (a2[3] + bav.w))};
            *(short4v*)(sYb + row * 264 + c0) = yv;
        }
    }
    __syncthreads();

    // ---- Stage C (transposed-output): newE = Y @ weo + beo -> sR bf16 ----
    {
        const short* pC = weoP + ((size_t)(wave * 8) * 64 + lane) * 8;
        short8 wC[8];
#pragma unroll
        for (int kb = 0; kb < 8; ++kb) wC[kb] = *(const short8*)(pC + (size_t)kb * 512);
        const int c0 = wave * 16 + quad * 4;
        const float4 bov = *(const float4*)(beo + c0);
#pragma unroll
        for (int rt = 0; rt < 4; ++rt) {
            const int row = rt * 16 + l15;
            f32x4 acc = (f32x4){0.f, 0.f, 0.f, 0.f};
#pragma unroll
            for (int kb = 0; kb < 8; ++kb) {
                short8 bf = *(const short8*)(sYb + row * 264 + quad * 8 + kb * 32);
                acc = __builtin_amdgcn_mfma_f32_16x16x32_bf16(wC[kb], bf, acc, 0, 0, 0);
            }
            short4v rv = {f2bs(acc[0] + bov.x), f2bs(acc[1] + bov.y),
                          f2bs(acc[2] + bov.z), f2bs(acc[3] + bov.w)};
            *(short4v*)(sR + row * 136 + c0) = rv;
        }
    }
    __syncthreads();

    // ---- LN1: sTb = bf16(LN(e + newE)*gne + bne) ----
    {
        float g0 = gne[lane], g1 = gne[lane + 64];
        float bn0 = bne[lane], bn1 = bne[lane + 64];
        for (int rr = 0; rr < 8; ++rr) {
            int row = wave * 8 + rr;
            float v0 = bs2f(sEb[row * 136 + lane]) + bs2f(sR[row * 136 + lane]);
            float v1 = bs2f(sEb[row * 136 + lane + 64]) + bs2f(sR[row * 136 + lane + 64]);
            float s1 = v0 + v1, s2 = v0 * v0 + v1 * v1;
            for (int off = 32; off; off >>= 1) {
                s1 += __shfl_down(s1, off);
                s2 += __shfl_down(s2, off);
            }
            s1 = __shfl(s1, 0); s2 = __shfl(s2, 0);
            float mean = s1 * 0.0078125f;
            float var = s2 * 0.0078125f - mean * mean;
            float rstd = rsqrtf(var + 1e-5f);
            sTb[row * 136 + lane]      = f2bs((v0 - mean) * rstd * g0 + bn0);
            sTb[row * 136 + lane + 64] = f2bs((v1 - mean) * rstd * g1 + bn1);
        }
    }
    __syncthreads();

    // ---- FF in 4 quarters of 128 cols; H2 accumulated in registers ----
    f32x4 accE[4];
#pragma unroll
    for (int p = 0; p < 4; ++p) accE[p] = (f32x4){0.f, 0.f, 0.f, 0.f};

    for (int q = 0; q < 4; ++q) {
        // H1q = relu(T @ we1[:, q*128:+128] + be1)  (1 col-tile per wave)
        {
            const int ctg = q * 8 + wave;
            const short* p1 = we1P + ((size_t)(ctg * 4) * 64 + lane) * 8;
            short8 w[4];
#pragma unroll
            for (int kb = 0; kb < 4; ++kb) w[kb] = *(const short8*)(p1 + (size_t)kb * 512);
            const int c0 = wave * 16 + quad * 4;
            const float4 b1v = *(const float4*)(be1 + ctg * 16 + quad * 4);
#pragma unroll
            for (int rt = 0; rt < 4; ++rt) {
                const int row = rt * 16 + l15;
                f32x4 acc = (f32x4){0.f, 0.f, 0.f, 0.f};
#pragma unroll
                for (int kb = 0; kb < 4; ++kb) {
                    short8 bf = *(const short8*)(sTb + row * 136 + quad * 8 + kb * 32);
                    acc = __builtin_amdgcn_mfma_f32_16x16x32_bf16(w[kb], bf, acc, 0, 0, 0);
                }
                short4v hv = {f2bs(fmaxf(acc[0] + b1v.x, 0.f)), f2bs(fmaxf(acc[1] + b1v.y, 0.f)),
                              f2bs(fmaxf(acc[2] + b1v.z, 0.f)), f2bs(fmaxf(acc[3] + b1v.w, 0.f))};
                *(short4v*)(sH1 + row * 136 + c0) = hv;
            }
        }
        __syncthreads();
        // H2 += H1q @ we2[q*128:+128, :]  (1 col-tile per wave)
        {
            const short* p2 = we2P + ((size_t)(wave * 16 + q * 4) * 64 + lane) * 8;
            short8 w[4];
#pragma unroll
            for (int kb = 0; kb < 4; ++kb) w[kb] = *(const short8*)(p2 + (size_t)kb * 512);
#pragma unroll
            for (int rt = 0; rt < 4; ++rt) {
                const int row = rt * 16 + l15;
#pragma unroll
                for (int kb = 0; kb < 4; ++kb) {
                    short8 bf = *(const short8*)(sH1 + row * 136 + quad * 8 + kb * 32);
                    accE[rt] = __builtin_amdgcn_mfma_f32_16x16x32_bf16(w[kb], bf, accE[rt], 0, 0, 0);
                }
            }
        }
        __syncthreads();
    }
    // epilogue -> sH2 f32 (over dead sTb/sYb region), float4 per lane
    {
        const int c0 = wave * 16 + quad * 4;
        const float4 b2v = *(const float4*)(be2 + c0);
#pragma unroll
        for (int rt = 0; rt < 4; ++rt) {
            const int row = rt * 16 + l15;
            float4 hv = {accE[rt][0] + b2v.x, accE[rt][1] + b2v.y,
                         accE[rt][2] + b2v.z, accE[rt][3] + b2v.w};
            *(float4*)(sH2 + (size_t)row * 132 + c0) = hv;
        }
    }
    __syncthreads();

    // ---- LN2 -> global ----
    {
        float g0 = gne[lane], g1 = gne[lane + 64];
        float bn0 = bne[lane], bn1 = bne[lane + 64];
        for (int rr = 0; rr < 8; ++rr) {
            int row = wave * 8 + rr;
            float v0 = bs2f(sEb[row * 136 + lane]) + sH2[row * 132 + lane];
            float v1 = bs2f(sEb[row * 136 + lane + 64]) + sH2[row * 132 + lane + 64];
            float s1 = v0 + v1, s2 = v0 * v0 + v1 * v1;
            for (int off = 32; off; off >>= 1) {
                s1 += __shfl_down(s1, off);
                s2 += __shfl_down(s2, off);
            }
            s1 = __shfl(s1, 0); s2 = __shfl(s2, 0);
            float mean = s1 * 0.0078125f;
            float var = s2 * 0.0078125f - mean * mean;
            float rstd = rsqrtf(var + 1e-5f);
            size_t o = (size_t)(r0 + row) * 128;
            eout[o + lane]      = (v0 - mean) * rstd * g0 + bn0;
            eout[o + lane + 64] = (v1 - mean) * rstd * g1 + bn1;
        }
    }
}

extern "C" void kernel_launch(void* const* d_in, const int* in_sizes, int n_in,
                              void* d_out, int out_size, void* d_ws, size_t ws_size,
                              hipStream_t stream) {
    const float* x   = (const float*)d_in[0];
    const float* e   = (const float*)d_in[1];
    const float* wq  = (const float*)d_in[2];
    const float* wk  = (const float*)d_in[3];
    const float* wv  = (const float*)d_in[4];
    const float* wem = (const float*)d_in[5];
    const float* wea = (const float*)d_in[6];
    const float* wxo = (const float*)d_in[7];
    const float* weo = (const float*)d_in[8];
    const float* wx1 = (const float*)d_in[9];
    const float* wx2 = (const float*)d_in[10];
    const float* we1 = (const float*)d_in[11];
    const float* we2 = (const float*)d_in[12];
    const float* bq  = (const float*)d_in[13];
    const float* bk  = (const float*)d_in[14];
    const float* bv  = (const float*)d_in[15];
    const float* bem = (const float*)d_in[16];
    const float* bea = (const float*)d_in[17];
    const float* bxo = (const float*)d_in[18];
    const float* beo = (const float*)d_in[19];
    const float* bx1 = (const float*)d_in[20];
    const float* bx2 = (const float*)d_in[21];
    const float* be1 = (const float*)d_in[22];
    const float* be2 = (const float*)d_in[23];
    const float* gnx = (const float*)d_in[24];
    const float* bnx = (const float*)d_in[25];
    const float* gne = (const float*)d_in[26];
    const float* bne = (const float*)d_in[27];

    float* out = (float*)d_out;  // x_out (262144) then e_out (16777216)

    float* ws = (float*)d_ws;
    float* Qb = ws;               // 262144 f32
    float* Kb = Qb + 262144;      // 262144 f32
    short* base = (short*)(Kb + 262144);
    short* wqP  = base;           // 65536
    short* wkP  = wqP + 65536;
    short* wvP  = wkP + 65536;
    short* wxoP = wvP + 65536;
    short* wx1P = wxoP + 65536;   // 262144
    short* wx2P = wx1P + 262144;  // 262144
    short* wemP = wx2P + 262144;  // 32768
    short* weaP = wemP + 32768;
    short* weoP = weaP + 32768;
    short* we1P = weoP + 32768;   // 65536
    short* we2P = we1P + 65536;   // 65536

    // ---- one pack launch for all 11 weights ----
    PackArgs pa;
    const float* Ws[11] = {wq, wk, wv, wxo, wx1, wx2, wem, wea, weo, we1, we2};
    short* Wps[11] = {wqP, wkP, wvP, wxoP, wx1P, wx2P, wemP, weaP, weoP, we1P, we2P};
    int Ks[11] = {256, 256, 256, 256, 256, 1024, 128, 128, 256, 128, 512};
    int Ns[11] = {256, 256, 256, 256, 1024, 256, 256, 256, 128, 512, 128};
    int acc = 0;
    for (int i = 0; i < 11; ++i) {
        pa.W[i] = Ws[i];
        pa.Wp[i] = Wps[i];
        pa.kdiv[i] = Ks[i] >> 5;
        pa.N[i] = Ns[i];
        pa.start[i] = acc;
        acc += (Ns[i] >> 4) * (Ks[i] >> 5) * 64;
    }
    pa.start[11] = acc;
    pack_all<<<(acc + 255) / 256, 256, 0, stream>>>(pa);

    // ---- Q/K GEMM (only cross-path dependency) ----
    qk_gemm<<<128, 256, 0, stream>>>(x, wqP, wkP, bq, bk, Qb, Kb);

    // ---- fused main: 32 x-blocks (first, overlap) + 2048 e-path ----
    fused_main<<<2080, 512, 0, stream>>>(
        x, e, Qb, Kb, wvP, wxoP, wx1P, wx2P, wemP, weaP, weoP, we1P, we2P,
        bv, bxo, bx1, bx2, bem, bea, beo, be1, be2,
        gnx, bnx, gne, bne, out, out + 262144);
}